// Round 1
// baseline (3504.468 us; speedup 1.0000x reference)
//
#include <hip/hip_runtime.h>
#include <hip/hip_bf16.h>

#define MDIM 4096
#define KDIM 4096
#define NDIM 14336

constexpr int BM = 128;
constexpr int BN = 128;
constexpr int BK = 64;   // == GROUP: one scale row per k-tile
constexpr int BKP = 72;  // padded LDS leading dim (16B-aligned rows, 2-way read conflicts = free)

typedef __attribute__((ext_vector_type(8))) short bf16x8;
typedef __attribute__((ext_vector_type(4))) float f32x4;

// round-to-nearest-even fp32 -> bf16
__device__ __forceinline__ unsigned short f2bf(float f) {
  unsigned u = __float_as_uint(f);
  return (unsigned short)((u + 0x7FFFu + ((u >> 16) & 1u)) >> 16);
}

__global__ __launch_bounds__(256, 2)
void marlin_int4_gemm(const float* __restrict__ X,
                      const int* __restrict__ Q,
                      const float* __restrict__ S,
                      float* __restrict__ Out) {
  __shared__ short As[BM * BKP];  // bf16 x-tile, [m][k] K-contiguous
  __shared__ short Bs[BN * BKP];  // bf16 w-tile, [n][k] K-contiguous (transposed during stage)

  const int bm = blockIdx.x * BM;   // x fastest: consecutive blocks share the B N-stripe (LLC reuse)
  const int bn = blockIdx.y * BN;

  const int tid  = threadIdx.x;
  const int lane = tid & 63;
  const int wave = tid >> 6;
  const int wm = (wave & 1) * 64;   // wave's 64x64 quadrant of the 128x128 tile
  const int wn = (wave >> 1) * 64;
  const int quad = lane >> 4;
  const int l16  = lane & 15;

  // B staging: thread owns one n-column (coalesced across lanes), 32 k-values
  const int nB  = tid & 127;
  const int krB = (tid >> 7) * 32;

  f32x4 acc[4][4];
#pragma unroll
  for (int i = 0; i < 4; ++i)
#pragma unroll
    for (int j = 0; j < 4; ++j)
      acc[i][j] = (f32x4){0.f, 0.f, 0.f, 0.f};

  for (int kt = 0; kt < KDIM / BK; ++kt) {
    const int k0 = kt * BK;
    // per-group dequant constants for this thread's column
    const float s    = S[kt * NDIM + bn + nB];
    const float bias = -8.0f * s;

    __syncthreads();  // previous tile's compute done before LDS overwrite

    // ---- stage A: 128x64 fp32 -> bf16, [m][k]
#pragma unroll
    for (int i = 0; i < 8; ++i) {
      const int idx4 = tid + (i << 8);
      const int row  = idx4 >> 4;
      const int col  = (idx4 & 15) << 2;
      const float4 v = *(const float4*)(X + (size_t)(bm + row) * KDIM + k0 + col);
      ushort4 b;
      b.x = f2bf(v.x); b.y = f2bf(v.y); b.z = f2bf(v.z); b.w = f2bf(v.w);
      *(ushort4*)(&As[row * BKP + col]) = b;
    }

    // ---- stage B: 64x128 int32 -> dequant -> bf16, transposed to [n][k]
    unsigned short wb[32];
#pragma unroll
    for (int j = 0; j < 32; ++j) {
      const int qv = Q[(size_t)(k0 + krB + j) * NDIM + bn + nB];
      wb[j] = f2bf((float)qv * s + bias);
    }
    {
      short* brow = &Bs[nB * BKP + krB];
#pragma unroll
      for (int c = 0; c < 4; ++c) {
        bf16x8 v;
#pragma unroll
        for (int e = 0; e < 8; ++e) v[e] = (short)wb[c * 8 + e];
        *(bf16x8*)(brow + c * 8) = v;
      }
    }

    __syncthreads();

    // ---- compute: 2 k-steps x 16 MFMAs per wave
#pragma unroll
    for (int kk = 0; kk < BK; kk += 32) {
      bf16x8 af[4], bfr[4];
#pragma unroll
      for (int i = 0; i < 4; ++i)
        af[i] = *(const bf16x8*)(&As[(wm + i * 16 + l16) * BKP + kk + quad * 8]);
#pragma unroll
      for (int j = 0; j < 4; ++j)
        bfr[j] = *(const bf16x8*)(&Bs[(wn + j * 16 + l16) * BKP + kk + quad * 8]);
#pragma unroll
      for (int i = 0; i < 4; ++i)
#pragma unroll
        for (int j = 0; j < 4; ++j)
          acc[i][j] = __builtin_amdgcn_mfma_f32_16x16x32_bf16(af[i], bfr[j], acc[i][j], 0, 0, 0);
    }
  }

  // ---- epilogue: C/D layout col=lane&15, row=quad*4+reg
#pragma unroll
  for (int i = 0; i < 4; ++i) {
    const int row0 = bm + wm + i * 16 + quad * 4;
#pragma unroll
    for (int j = 0; j < 4; ++j) {
      const int col = bn + wn + j * 16 + l16;
#pragma unroll
      for (int r = 0; r < 4; ++r)
        Out[(size_t)(row0 + r) * NDIM + col] = acc[i][j][r];
    }
  }
}

extern "C" void kernel_launch(void* const* d_in, const int* in_sizes, int n_in,
                              void* d_out, int out_size, void* d_ws, size_t ws_size,
                              hipStream_t stream) {
  const float* X = (const float*)d_in[0];
  const int*   Q = (const int*)d_in[1];
  const float* S = (const float*)d_in[2];
  // d_in[3] = group_size (=64), baked in as BK
  float* Out = (float*)d_out;
  dim3 grid(MDIM / BM, NDIM / BN);  // (32, 112)
  marlin_int4_gemm<<<grid, dim3(256), 0, stream>>>(X, Q, S, Out);
}

// Round 2
// 909.778 us; speedup vs baseline: 3.8520x; 3.8520x over previous
//
#include <hip/hip_runtime.h>

#define MDIM 4096
#define KDIM 4096
#define NDIM 14336

typedef __attribute__((ext_vector_type(8))) short bf16x8;
typedef __attribute__((ext_vector_type(4))) float f32x4;

// round-to-nearest-even fp32 -> bf16
__device__ __forceinline__ unsigned short f2bf(float f) {
  unsigned u = __float_as_uint(f);
  return (unsigned short)((u + 0x7FFFu + ((u >> 16) & 1u)) >> 16);
}

// async 16B global -> LDS (lane i lands at ldsbase + i*16)
__device__ __forceinline__ void async_copy16(const void* g, void* l) {
  __builtin_amdgcn_global_load_lds((const __attribute__((address_space(1))) unsigned*)g,
                                   (__attribute__((address_space(3))) unsigned*)l, 16, 0, 0);
}

// ---------------- P1: X fp32 -> bf16 ----------------
__global__ __launch_bounds__(256) void cvt_x_kernel(const float* __restrict__ X,
                                                    short* __restrict__ Xb) {
  const int i = blockIdx.x * 256 + threadIdx.x;  // 8 floats per thread
  const float4* p = (const float4*)X + (size_t)i * 2;
  const float4 a = p[0], b = p[1];
  bf16x8 v;
  v[0] = f2bf(a.x); v[1] = f2bf(a.y); v[2] = f2bf(a.z); v[3] = f2bf(a.w);
  v[4] = f2bf(b.x); v[5] = f2bf(b.y); v[6] = f2bf(b.z); v[7] = f2bf(b.w);
  *((bf16x8*)Xb + i) = v;
}

// ---------------- P2: dequant Q[K][N] int32 -> Wt[N][K] bf16 (transposed) ----------------
constexpr int TP = 70;  // LDS row pad (shorts): 35 dwords/row -> low-conflict both phases
__global__ __launch_bounds__(256) void dequant_w_kernel(const int* __restrict__ Q,
                                                        const float* __restrict__ S,
                                                        short* __restrict__ Wt) {
  __shared__ short Ls[64 * TP];  // [n][k]
  const int k0 = blockIdx.x * 64;
  const int n0 = blockIdx.y * 64;
  const int t  = threadIdx.x;
  const int g  = k0 >> 6;  // one scale group per 64-k tile (GROUP=64)

  // phase 1: read 64x64 int tile coalesced, dequant, write transposed into LDS
  const int c4 = (t & 15) * 4;
  const int r0 = t >> 4;
  const float4 s4 = *(const float4*)(S + (size_t)g * NDIM + n0 + c4);
#pragma unroll
  for (int i = 0; i < 4; ++i) {
    const int r = r0 + i * 16;
    const int4 q = *(const int4*)(Q + (size_t)(k0 + r) * NDIM + n0 + c4);
    Ls[(c4 + 0) * TP + r] = (short)f2bf((float)(q.x - 8) * s4.x);
    Ls[(c4 + 1) * TP + r] = (short)f2bf((float)(q.y - 8) * s4.y);
    Ls[(c4 + 2) * TP + r] = (short)f2bf((float)(q.z - 8) * s4.z);
    Ls[(c4 + 3) * TP + r] = (short)f2bf((float)(q.w - 8) * s4.w);
  }
  __syncthreads();

  // phase 2: write out [n][k] rows, coalesced (4 lanes cover one 128B row)
  const int nr = t >> 2;
  const int ks = (t & 3) * 16;
  const short* lr = &Ls[nr * TP + ks];
  bf16x8 v0, v1;
#pragma unroll
  for (int j = 0; j < 8; ++j) { v0[j] = lr[j]; v1[j] = lr[8 + j]; }
  short* wp = Wt + (size_t)(n0 + nr) * KDIM + k0 + ks;
  *(bf16x8*)wp = v0;
  *(bf16x8*)(wp + 8) = v1;
}

// ---------------- GEMM: Xb[M][K] bf16 x Wt[N][K] bf16 -> Out[M][N] fp32 ----------------
__global__ __launch_bounds__(256, 2)
void gemm_bf16tt(const short* __restrict__ Xb, const short* __restrict__ Wt,
                 float* __restrict__ Out) {
  __shared__ short As[128 * 64];  // [m][k], unpadded (global_load_lds lane-order)
  __shared__ short Bs[128 * 64];  // [n][k]

  const int bm = blockIdx.x * 128;
  const int bn = blockIdx.y * 128;
  const int tid = threadIdx.x, lane = tid & 63, wave = tid >> 6;
  const int wm = (wave & 1) * 64, wn = (wave >> 1) * 64;
  const int quad = lane >> 4, l16 = lane & 15;

  f32x4 acc[4][4];
#pragma unroll
  for (int i = 0; i < 4; ++i)
#pragma unroll
    for (int j = 0; j < 4; ++j) acc[i][j] = (f32x4){0.f, 0.f, 0.f, 0.f};

  // staging chunk: chunk c = p*256 + tid covers row c>>3, k-offset (c&7)*8
  const int row0 = tid >> 3;
  const int kof  = (tid & 7) * 8;
  const size_t aoff = (size_t)(bm + row0) * KDIM + kof;
  const size_t boff = (size_t)(bn + row0) * KDIM + kof;

  for (int kt = 0; kt < KDIM / 64; ++kt) {
    const int k0 = kt * 64;
    __syncthreads();  // previous tile's compute done
#pragma unroll
    for (int p = 0; p < 4; ++p) {
      const short* ga = Xb + aoff + (size_t)p * 32 * KDIM + k0;
      const short* gb = Wt + boff + (size_t)p * 32 * KDIM + k0;
      short* la = &As[(p * 256 + wave * 64) * 8];  // wave-uniform LDS base
      short* lb = &Bs[(p * 256 + wave * 64) * 8];
      async_copy16(ga, la);
      async_copy16(gb, lb);
    }
    __syncthreads();  // staging complete

#pragma unroll
    for (int kk = 0; kk < 64; kk += 32) {
      bf16x8 af[4], bfr[4];
#pragma unroll
      for (int i = 0; i < 4; ++i)
        af[i] = *(const bf16x8*)&As[(wm + i * 16 + l16) * 64 + kk + quad * 8];
#pragma unroll
      for (int j = 0; j < 4; ++j)
        bfr[j] = *(const bf16x8*)&Bs[(wn + j * 16 + l16) * 64 + kk + quad * 8];
#pragma unroll
      for (int i = 0; i < 4; ++i)
#pragma unroll
        for (int j = 0; j < 4; ++j)
          acc[i][j] = __builtin_amdgcn_mfma_f32_16x16x32_bf16(af[i], bfr[j], acc[i][j], 0, 0, 0);
    }
  }

  // epilogue: C/D layout col=lane&15, row=quad*4+reg
#pragma unroll
  for (int i = 0; i < 4; ++i) {
    const int r0 = bm + wm + i * 16 + quad * 4;
#pragma unroll
    for (int j = 0; j < 4; ++j) {
      const int col = bn + wn + j * 16 + l16;
#pragma unroll
      for (int r = 0; r < 4; ++r)
        Out[(size_t)(r0 + r) * NDIM + col] = acc[i][j][r];
    }
  }
}

// ---------------- fallback (round-1 fused kernel) ----------------
constexpr int BKP = 72;
__global__ __launch_bounds__(256, 2)
void marlin_int4_gemm(const float* __restrict__ X, const int* __restrict__ Q,
                      const float* __restrict__ S, float* __restrict__ Out) {
  __shared__ short As[128 * BKP];
  __shared__ short Bs[128 * BKP];
  const int bm = blockIdx.x * 128, bn = blockIdx.y * 128;
  const int tid = threadIdx.x, lane = tid & 63, wave = tid >> 6;
  const int wm = (wave & 1) * 64, wn = (wave >> 1) * 64;
  const int quad = lane >> 4, l16 = lane & 15;
  const int nB = tid & 127, krB = (tid >> 7) * 32;
  f32x4 acc[4][4];
#pragma unroll
  for (int i = 0; i < 4; ++i)
#pragma unroll
    for (int j = 0; j < 4; ++j) acc[i][j] = (f32x4){0.f, 0.f, 0.f, 0.f};
  for (int kt = 0; kt < KDIM / 64; ++kt) {
    const int k0 = kt * 64;
    const float s = S[kt * NDIM + bn + nB];
    const float bias = -8.0f * s;
    __syncthreads();
#pragma unroll
    for (int i = 0; i < 8; ++i) {
      const int idx4 = tid + (i << 8);
      const int row = idx4 >> 4, col = (idx4 & 15) << 2;
      const float4 v = *(const float4*)(X + (size_t)(bm + row) * KDIM + k0 + col);
      ushort4 b;
      b.x = f2bf(v.x); b.y = f2bf(v.y); b.z = f2bf(v.z); b.w = f2bf(v.w);
      *(ushort4*)(&As[row * BKP + col]) = b;
    }
    unsigned short wb[32];
#pragma unroll
    for (int j = 0; j < 32; ++j) {
      const int qv = Q[(size_t)(k0 + krB + j) * NDIM + bn + nB];
      wb[j] = f2bf((float)qv * s + bias);
    }
    {
      short* brow = &Bs[nB * BKP + krB];
#pragma unroll
      for (int c = 0; c < 4; ++c) {
        bf16x8 v;
#pragma unroll
        for (int e = 0; e < 8; ++e) v[e] = (short)wb[c * 8 + e];
        *(bf16x8*)(brow + c * 8) = v;
      }
    }
    __syncthreads();
#pragma unroll
    for (int kk = 0; kk < 64; kk += 32) {
      bf16x8 af[4], bfr[4];
#pragma unroll
      for (int i = 0; i < 4; ++i)
        af[i] = *(const bf16x8*)&As[(wm + i * 16 + l16) * BKP + kk + quad * 8];
#pragma unroll
      for (int j = 0; j < 4; ++j)
        bfr[j] = *(const bf16x8*)&Bs[(wn + j * 16 + l16) * BKP + kk + quad * 8];
#pragma unroll
      for (int i = 0; i < 4; ++i)
#pragma unroll
        for (int j = 0; j < 4; ++j)
          acc[i][j] = __builtin_amdgcn_mfma_f32_16x16x32_bf16(af[i], bfr[j], acc[i][j], 0, 0, 0);
    }
  }
#pragma unroll
  for (int i = 0; i < 4; ++i) {
    const int r0 = bm + wm + i * 16 + quad * 4;
#pragma unroll
    for (int j = 0; j < 4; ++j) {
      const int col = bn + wn + j * 16 + l16;
#pragma unroll
      for (int r = 0; r < 4; ++r)
        Out[(size_t)(r0 + r) * NDIM + col] = acc[i][j][r];
    }
  }
}

extern "C" void kernel_launch(void* const* d_in, const int* in_sizes, int n_in,
                              void* d_out, int out_size, void* d_ws, size_t ws_size,
                              hipStream_t stream) {
  const float* X = (const float*)d_in[0];
  const int*   Q = (const int*)d_in[1];
  const float* S = (const float*)d_in[2];
  float* Out = (float*)d_out;

  const size_t xb_elems = (size_t)MDIM * KDIM;
  const size_t wt_elems = (size_t)NDIM * KDIM;
  const size_t need = (xb_elems + wt_elems) * sizeof(short);

  if (ws_size >= need) {
    short* Xb = (short*)d_ws;
    short* Wt = Xb + xb_elems;
    cvt_x_kernel<<<(int)(xb_elems / 8 / 256), 256, 0, stream>>>(X, Xb);
    dequant_w_kernel<<<dim3(KDIM / 64, NDIM / 64), 256, 0, stream>>>(Q, S, Wt);
    gemm_bf16tt<<<dim3(MDIM / 128, NDIM / 128), 256, 0, stream>>>(Xb, Wt, Out);
  } else {
    marlin_int4_gemm<<<dim3(MDIM / 128, NDIM / 128), 256, 0, stream>>>(X, Q, S, Out);
  }
}

// Round 3
// 847.020 us; speedup vs baseline: 4.1374x; 1.0741x over previous
//
#include <hip/hip_runtime.h>

#define MDIM 4096
#define KDIM 4096
#define NDIM 14336

typedef __attribute__((ext_vector_type(8))) short bf16x8;
typedef __attribute__((ext_vector_type(4))) short bf16x4;
typedef __attribute__((ext_vector_type(4))) float f32x4;

// round-to-nearest-even fp32 -> bf16
__device__ __forceinline__ unsigned short f2bf(float f) {
  unsigned u = __float_as_uint(f);
  return (unsigned short)((u + 0x7FFFu + ((u >> 16) & 1u)) >> 16);
}

// async 16B global -> LDS (lane i lands at ldsbase + i*16)
__device__ __forceinline__ void async_copy16(const void* g, void* l) {
  __builtin_amdgcn_global_load_lds((const __attribute__((address_space(1))) unsigned*)g,
                                   (__attribute__((address_space(3))) unsigned*)l, 16, 0, 0);
}

// ---------------- P1: X fp32 -> bf16 ----------------
__global__ __launch_bounds__(256) void cvt_x_kernel(const float* __restrict__ X,
                                                    short* __restrict__ Xb) {
  const int i = blockIdx.x * 256 + threadIdx.x;  // 8 floats per thread
  const float4* p = (const float4*)X + (size_t)i * 2;
  const float4 a = p[0], b = p[1];
  bf16x8 v;
  v[0] = f2bf(a.x); v[1] = f2bf(a.y); v[2] = f2bf(a.z); v[3] = f2bf(a.w);
  v[4] = f2bf(b.x); v[5] = f2bf(b.y); v[6] = f2bf(b.z); v[7] = f2bf(b.w);
  *((bf16x8*)Xb + i) = v;
}

// ---------------- P2: dequant Q[K][N] int32 -> Wt[N][K] bf16 (transposed) ----------------
// Register-transposed 4x4 blocks: 4 int4 loads + 4 ds_write_b64 + 4 ds_read_b64 per thread.
constexpr int TPD = 76;  // shorts; 152 B row stride: b64-aligned, non-pow2 banks
__global__ __launch_bounds__(256) void dequant_w_kernel(const int* __restrict__ Q,
                                                        const float* __restrict__ S,
                                                        short* __restrict__ Wt) {
  __shared__ short Ls[64 * TPD];  // [n][k]
  const int k0 = blockIdx.x * 64;
  const int n0 = blockIdx.y * 64;
  const int t  = threadIdx.x;
  const int g  = k0 >> 6;  // GROUP == 64

  // phase 1: 4x4 block at (k0+rb, n0+n4): coalesced int4 row reads
  const int n4 = (t & 15) * 4;
  const int rb = (t >> 4) * 4;
  const float4 s4 = *(const float4*)(S + (size_t)g * NDIM + n0 + n4);
  int4 q[4];
#pragma unroll
  for (int i = 0; i < 4; ++i)
    q[i] = *(const int4*)(Q + (size_t)(k0 + rb + i) * NDIM + n0 + n4);
  // transpose in registers: column j -> 4 consecutive k
  {
    bf16x4 v;
    v[0] = (short)f2bf((float)(q[0].x - 8) * s4.x);
    v[1] = (short)f2bf((float)(q[1].x - 8) * s4.x);
    v[2] = (short)f2bf((float)(q[2].x - 8) * s4.x);
    v[3] = (short)f2bf((float)(q[3].x - 8) * s4.x);
    *(bf16x4*)&Ls[(n4 + 0) * TPD + rb] = v;
    v[0] = (short)f2bf((float)(q[0].y - 8) * s4.y);
    v[1] = (short)f2bf((float)(q[1].y - 8) * s4.y);
    v[2] = (short)f2bf((float)(q[2].y - 8) * s4.y);
    v[3] = (short)f2bf((float)(q[3].y - 8) * s4.y);
    *(bf16x4*)&Ls[(n4 + 1) * TPD + rb] = v;
    v[0] = (short)f2bf((float)(q[0].z - 8) * s4.z);
    v[1] = (short)f2bf((float)(q[1].z - 8) * s4.z);
    v[2] = (short)f2bf((float)(q[2].z - 8) * s4.z);
    v[3] = (short)f2bf((float)(q[3].z - 8) * s4.z);
    *(bf16x4*)&Ls[(n4 + 2) * TPD + rb] = v;
    v[0] = (short)f2bf((float)(q[0].w - 8) * s4.w);
    v[1] = (short)f2bf((float)(q[1].w - 8) * s4.w);
    v[2] = (short)f2bf((float)(q[2].w - 8) * s4.w);
    v[3] = (short)f2bf((float)(q[3].w - 8) * s4.w);
    *(bf16x4*)&Ls[(n4 + 3) * TPD + rb] = v;
  }
  __syncthreads();

  // phase 2: row nr, 16 shorts starting kc; 4 lanes cover one 128 B row segment
  const int nr = t >> 2;
  const int kc = (t & 3) * 16;
  const short* lr = &Ls[nr * TPD + kc];
  bf16x4 a0 = *(const bf16x4*)(lr + 0);
  bf16x4 a1 = *(const bf16x4*)(lr + 4);
  bf16x4 a2 = *(const bf16x4*)(lr + 8);
  bf16x4 a3 = *(const bf16x4*)(lr + 12);
  bf16x8 v0, v1;
#pragma unroll
  for (int j = 0; j < 4; ++j) { v0[j] = a0[j]; v0[4 + j] = a1[j]; v1[j] = a2[j]; v1[4 + j] = a3[j]; }
  short* wp = Wt + (size_t)(n0 + nr) * KDIM + k0 + kc;
  *(bf16x8*)wp = v0;
  *(bf16x8*)(wp + 8) = v1;
}

// ---------------- GEMM: Xb[M][K] x Wt[N][K] -> Out[M][N], XOR-swizzled LDS ----------------
// LDS row r (128 B = 8 slots of 16 B): slot s holds global k-chunk (s ^ (r&7)).
// Bank spread for fragment reads: slot = (kk/8+quad) ^ (l16&7) -> 8 lanes per
// bank-quad (uniform, the b128 minimum) instead of 16 (old 16-way conflict).
__global__ __launch_bounds__(256, 2)
void gemm_bf16tt(const short* __restrict__ Xb, const short* __restrict__ Wt,
                 float* __restrict__ Out) {
  __shared__ short As[128 * 64];
  __shared__ short Bs[128 * 64];

  const int bm = blockIdx.x * 128;
  const int bn = blockIdx.y * 128;
  const int tid = threadIdx.x, lane = tid & 63, wave = tid >> 6;
  const int wm = (wave & 1) * 64, wn = (wave >> 1) * 64;
  const int quad = lane >> 4, l16 = lane & 15;
  const int lx = l16 & 7;  // row&7 for fragment rows

  f32x4 acc[4][4];
#pragma unroll
  for (int i = 0; i < 4; ++i)
#pragma unroll
    for (int j = 0; j < 4; ++j) acc[i][j] = (f32x4){0.f, 0.f, 0.f, 0.f};

  // staging: chunk (p*256+tid) -> LDS row p*32 + (tid>>3), slot tid&7
  // global k-chunk is XOR-swizzled: kof = ((tid&7) ^ (row&7)) * 8
  const int row0 = tid >> 3;
  const int kof  = (((tid & 7) ^ (row0 & 7))) * 8;
  const size_t aoff = (size_t)(bm + row0) * KDIM + kof;
  const size_t boff = (size_t)(bn + row0) * KDIM + kof;
  short* const la = &As[(wave * 64) * 8];  // wave-uniform base
  short* const lb = &Bs[(wave * 64) * 8];

  for (int kt = 0; kt < KDIM / 64; ++kt) {
    const int k0 = kt * 64;
    __syncthreads();  // previous tile's compute done
#pragma unroll
    for (int p = 0; p < 4; ++p) {
      async_copy16(Xb + aoff + (size_t)p * 32 * KDIM + k0, la + p * 2048);
      async_copy16(Wt + boff + (size_t)p * 32 * KDIM + k0, lb + p * 2048);
    }
    __syncthreads();  // staging complete

#pragma unroll
    for (int kk = 0; kk < 64; kk += 32) {
      const int sbase = kk >> 3;
      bf16x8 af[4], bfr[4];
#pragma unroll
      for (int i = 0; i < 4; ++i)
        af[i] = *(const bf16x8*)&As[(wm + i * 16 + l16) * 64 + (((sbase + quad) ^ lx) << 3)];
#pragma unroll
      for (int j = 0; j < 4; ++j)
        bfr[j] = *(const bf16x8*)&Bs[(wn + j * 16 + l16) * 64 + (((sbase + quad) ^ lx) << 3)];
#pragma unroll
      for (int i = 0; i < 4; ++i)
#pragma unroll
        for (int j = 0; j < 4; ++j)
          acc[i][j] = __builtin_amdgcn_mfma_f32_16x16x32_bf16(af[i], bfr[j], acc[i][j], 0, 0, 0);
    }
  }

  // epilogue: C/D layout col=lane&15, row=quad*4+reg
#pragma unroll
  for (int i = 0; i < 4; ++i) {
    const int r0 = bm + wm + i * 16 + quad * 4;
#pragma unroll
    for (int j = 0; j < 4; ++j) {
      const int col = bn + wn + j * 16 + l16;
#pragma unroll
      for (int r = 0; r < 4; ++r)
        Out[(size_t)(r0 + r) * NDIM + col] = acc[i][j][r];
    }
  }
}

// ---------------- fallback (fused, used only if ws too small) ----------------
constexpr int BKP = 72;
__global__ __launch_bounds__(256, 2)
void marlin_int4_gemm(const float* __restrict__ X, const int* __restrict__ Q,
                      const float* __restrict__ S, float* __restrict__ Out) {
  __shared__ short As[128 * BKP];
  __shared__ short Bs[128 * BKP];
  const int bm = blockIdx.x * 128, bn = blockIdx.y * 128;
  const int tid = threadIdx.x, lane = tid & 63, wave = tid >> 6;
  const int wm = (wave & 1) * 64, wn = (wave >> 1) * 64;
  const int quad = lane >> 4, l16 = lane & 15;
  const int nB = tid & 127, krB = (tid >> 7) * 32;
  f32x4 acc[4][4];
#pragma unroll
  for (int i = 0; i < 4; ++i)
#pragma unroll
    for (int j = 0; j < 4; ++j) acc[i][j] = (f32x4){0.f, 0.f, 0.f, 0.f};
  for (int kt = 0; kt < KDIM / 64; ++kt) {
    const int k0 = kt * 64;
    const float s = S[kt * NDIM + bn + nB];
    const float bias = -8.0f * s;
    __syncthreads();
#pragma unroll
    for (int i = 0; i < 8; ++i) {
      const int idx4 = tid + (i << 8);
      const int row = idx4 >> 4, col = (idx4 & 15) << 2;
      const float4 v = *(const float4*)(X + (size_t)(bm + row) * KDIM + k0 + col);
      ushort4 b;
      b.x = f2bf(v.x); b.y = f2bf(v.y); b.z = f2bf(v.z); b.w = f2bf(v.w);
      *(ushort4*)(&As[row * BKP + col]) = b;
    }
    unsigned short wb[32];
#pragma unroll
    for (int j = 0; j < 32; ++j) {
      const int qv = Q[(size_t)(k0 + krB + j) * NDIM + bn + nB];
      wb[j] = f2bf((float)qv * s + bias);
    }
    {
      short* brow = &Bs[nB * BKP + krB];
#pragma unroll
      for (int c = 0; c < 4; ++c) {
        bf16x8 v;
#pragma unroll
        for (int e = 0; e < 8; ++e) v[e] = (short)wb[c * 8 + e];
        *(bf16x8*)(brow + c * 8) = v;
      }
    }
    __syncthreads();
#pragma unroll
    for (int kk = 0; kk < 64; kk += 32) {
      bf16x8 af[4], bfr[4];
#pragma unroll
      for (int i = 0; i < 4; ++i)
        af[i] = *(const bf16x8*)&As[(wm + i * 16 + l16) * BKP + kk + quad * 8];
#pragma unroll
      for (int j = 0; j < 4; ++j)
        bfr[j] = *(const bf16x8*)&Bs[(wn + j * 16 + l16) * BKP + kk + quad * 8];
#pragma unroll
      for (int i = 0; i < 4; ++i)
#pragma unroll
        for (int j = 0; j < 4; ++j)
          acc[i][j] = __builtin_amdgcn_mfma_f32_16x16x32_bf16(af[i], bfr[j], acc[i][j], 0, 0, 0);
    }
  }
#pragma unroll
  for (int i = 0; i < 4; ++i) {
    const int r0 = bm + wm + i * 16 + quad * 4;
#pragma unroll
    for (int j = 0; j < 4; ++j) {
      const int col = bn + wn + j * 16 + l16;
#pragma unroll
      for (int r = 0; r < 4; ++r)
        Out[(size_t)(r0 + r) * NDIM + col] = acc[i][j][r];
    }
  }
}

extern "C" void kernel_launch(void* const* d_in, const int* in_sizes, int n_in,
                              void* d_out, int out_size, void* d_ws, size_t ws_size,
                              hipStream_t stream) {
  const float* X = (const float*)d_in[0];
  const int*   Q = (const int*)d_in[1];
  const float* S = (const float*)d_in[2];
  float* Out = (float*)d_out;

  const size_t xb_elems = (size_t)MDIM * KDIM;
  const size_t wt_elems = (size_t)NDIM * KDIM;
  const size_t need = (xb_elems + wt_elems) * sizeof(short);

  if (ws_size >= need) {
    short* Xb = (short*)d_ws;
    short* Wt = Xb + xb_elems;
    cvt_x_kernel<<<(int)(xb_elems / 8 / 256), 256, 0, stream>>>(X, Xb);
    dequant_w_kernel<<<dim3(KDIM / 64, NDIM / 64), 256, 0, stream>>>(Q, S, Wt);
    gemm_bf16tt<<<dim3(MDIM / 128, NDIM / 128), 256, 0, stream>>>(Xb, Wt, Out);
  } else {
    marlin_int4_gemm<<<dim3(MDIM / 128, NDIM / 128), 256, 0, stream>>>(X, Q, S, Out);
  }
}